// Round 1
// baseline (3067.971 us; speedup 1.0000x reference)
//
#include <hip/hip_runtime.h>
#include <math.h>

// ---- problem constants ----
static constexpr int B_   = 32;
static constexpr int HIN  = 36;
static constexpr int SP1  = 28*28;      // 784, conv1 out spatial
static constexpr int SP2  = 400;        // 20x20, prim out spatial
static constexpr int PDIM = 12800;      // 32ch*400
static constexpr int OSD  = 160;        // 10*16
static constexpr int NBLK_A = 200;      // pass-A blocks (64 p each)

// ---------------- K0: prim_w[co][ci][k] -> Wk[k][ci][co] ----------------
__global__ void k_transpose_w(const float* __restrict__ w, float* __restrict__ Wk) {
    __shared__ float sT[9][32][33];
    int co0 = blockIdx.x*32, ci0 = blockIdx.y*32, k0 = blockIdx.z*9;
    int tid = threadIdx.x;
    for (int r = 0; r < 4; ++r) {
        int idx = r*256 + tid;
        int co = idx >> 5, ci = idx & 31;
        const float* src = w + ((size_t)(co0+co)*256 + (ci0+ci))*81 + k0;
        #pragma unroll
        for (int k = 0; k < 9; ++k) sT[k][ci][co] = src[k];
    }
    __syncthreads();
    for (int k = 0; k < 9; ++k)
        for (int r = 0; r < 4; ++r) {
            int idx = r*256 + tid;
            int ci = idx >> 5, co = idx & 31;
            Wk[(size_t)(k0+k)*65536 + (ci0+ci)*256 + co0 + co] = sT[k][ci][co];
        }
}

// ---------------- K1: conv1 + bias + relu -> h[b][co][28][28] ----------------
__global__ void k_conv1(const float* __restrict__ x, const float* __restrict__ w,
                        const float* __restrict__ bias, float* __restrict__ h) {
    __shared__ float sx[HIN*HIN];   // 1296
    __shared__ float sw[16*81];     // 1296
    int b = blockIdx.x, cog = blockIdx.y;
    int tid = threadIdx.x;
    for (int i = tid; i < 1296; i += 256) {
        sx[i] = x[b*1296 + i];
        sw[i] = w[cog*1296 + i];    // [co][81] contiguous within the 16-co group
    }
    __syncthreads();
    for (int pos = tid; pos < SP1; pos += 256) {
        int y = pos / 28, xx = pos - y*28;
        float acc[16];
        #pragma unroll
        for (int c = 0; c < 16; ++c) acc[c] = 0.f;
        for (int ky = 0; ky < 9; ++ky) {
            #pragma unroll
            for (int kx = 0; kx < 9; ++kx) {
                float xv = sx[(y+ky)*36 + xx + kx];
                #pragma unroll
                for (int c = 0; c < 16; ++c)
                    acc[c] += xv * sw[c*81 + ky*9 + kx];
            }
        }
        #pragma unroll
        for (int c = 0; c < 16; ++c) {
            float r = acc[c] + bias[cog*16 + c];
            h[((size_t)(b*256 + cog*16 + c))*SP1 + pos] = r > 0.f ? r : 0.f;
        }
    }
}

// ---------------- K2: primary conv as 81 shifted GEMMs ----------------
// C[co][n] = sum_{ky,kx,ci} Wk[k][ci][co] * h[b(n)][ci][y(n)+ky][x(n)+kx]
// block tile 64co x 128n, thread tile 4x8, writes up[b][unit][ch*400+sp] (+bias)
__global__ __launch_bounds__(256) void k_prim_gemm(const float* __restrict__ h,
        const float* __restrict__ Wk, const float* __restrict__ bias,
        float* __restrict__ up) {
    __shared__ float sA[32][64];    // [ci][co]
    __shared__ float sB[32][128];   // [ci][n]
    int tid = threadIdx.x;
    int n0  = blockIdx.x * 128;
    int coB = blockIdx.y * 64;
    // B-stage decode (fixed n column per thread)
    int nl = tid & 127;
    int ng = n0 + nl;
    int bN = ng / 400;
    int rem = ng - bN*400;
    int yN = rem / 20;
    int xN = rem - yN*20;
    size_t hbase = (size_t)bN*200704 + yN*28 + xN;
    int ciStart = (tid >> 7);            // 0 or 1
    int ty = tid >> 4, tx = tid & 15;    // compute mapping
    float acc[4][8];
    #pragma unroll
    for (int i = 0; i < 4; ++i)
        #pragma unroll
        for (int j = 0; j < 8; ++j) acc[i][j] = 0.f;

    for (int ky = 0; ky < 9; ++ky) {
      for (int kx = 0; kx < 9; ++kx) {
        int kk = ky*9 + kx;
        const float*  hb  = h + hbase + ky*28 + kx;
        const float4* wkb = (const float4*)(Wk + (size_t)kk*65536);
        for (int cc = 0; cc < 8; ++cc) {
            int ci0 = cc*32;
            __syncthreads();
            #pragma unroll
            for (int r = 0; r < 2; ++r) {           // stage A (float4)
                int v = r*256 + tid;
                int ciA = v >> 4, co4 = v & 15;
                float4 av = wkb[(ci0+ciA)*64 + (coB>>2) + co4];
                *(float4*)&sA[ciA][co4*4] = av;
            }
            #pragma unroll
            for (int j = 0; j < 16; ++j) {          // stage B
                int cis = ciStart + 2*j;
                sB[cis][nl] = hb[(size_t)(ci0+cis)*784];
            }
            __syncthreads();
            #pragma unroll
            for (int ci = 0; ci < 32; ++ci) {
                float4 a  = *(const float4*)&sA[ci][ty*4];
                float4 b0 = *(const float4*)&sB[ci][tx*8];
                float4 b1 = *(const float4*)&sB[ci][tx*8+4];
                float av[4] = {a.x,a.y,a.z,a.w};
                float bv[8] = {b0.x,b0.y,b0.z,b0.w,b1.x,b1.y,b1.z,b1.w};
                #pragma unroll
                for (int i = 0; i < 4; ++i)
                    #pragma unroll
                    for (int j = 0; j < 8; ++j) acc[i][j] += av[i]*bv[j];
            }
        }
      }
    }
    // epilogue: + bias, scatter into up[b][unit][ch*400 + sp]
    #pragma unroll
    for (int i = 0; i < 4; ++i) {
        int co = coB + ty*4 + i;
        int unit = co >> 5, ch = co & 31;
        float bb = bias[co];
        #pragma unroll
        for (int j = 0; j < 8; ++j) {
            int nn = n0 + tx*8 + j;
            int bn = nn / 400;
            int rr = nn - bn*400;
            up[(size_t)(bn*8 + unit)*PDIM + ch*400 + rr] = acc[i][j] + bb;
        }
    }
}

// ---------------- K3a: squash scale per (b,unit) ----------------
__global__ void k_scale(const float* __restrict__ up, float* __restrict__ scl) {
    __shared__ float red[256];
    int bu = blockIdx.x, tid = threadIdx.x;
    const float* base = up + (size_t)bu*PDIM;
    float s = 0.f;
    for (int i = tid; i < PDIM; i += 256) { float v = base[i]; s += v*v; }
    red[tid] = s; __syncthreads();
    for (int st = 128; st > 0; st >>= 1) {
        if (tid < st) red[tid] += red[tid+st];
        __syncthreads();
    }
    if (tid == 0) {
        float msq = red[0];
        scl[bu] = sqrtf(msq) / (1.f + msq);   // s * mag/(1+mag^2)
    }
}

// ---------------- K3b: xq[p][b*8+u] = up[b][u][p] * scl[b][u] ----------------
__global__ void k_xq(const float* __restrict__ up, const float* __restrict__ scl,
                     float* __restrict__ xq) {
    __shared__ float sT[32][257];
    __shared__ float sS[256];
    int p0 = blockIdx.x*32, tid = threadIdx.x;
    sS[tid] = scl[tid];
    __syncthreads();
    for (int r = 0; r < 32; ++r) {
        int e = r*256 + tid;
        int bu = e >> 5, pi = e & 31;
        sT[pi][bu] = up[(size_t)bu*PDIM + p0 + pi] * sS[bu];
    }
    __syncthreads();
    for (int r = 0; r < 32; ++r)
        xq[(size_t)(p0+r)*256 + tid] = sT[r][tid];
}

// ---------------- K4: softmax-over-P stats per o ----------------
__global__ void k_softmax_stats(const float* __restrict__ bij, float* __restrict__ cstat) {
    __shared__ float red[256];
    int o = blockIdx.x, tid = threadIdx.x;
    float m = -1e30f;
    for (int i = tid; i < PDIM; i += 256) m = fmaxf(m, bij[i*10 + o]);
    red[tid] = m; __syncthreads();
    for (int st = 128; st > 0; st >>= 1) {
        if (tid < st) red[tid] = fmaxf(red[tid], red[tid+st]);
        __syncthreads();
    }
    m = red[0]; __syncthreads();
    float s = 0.f;
    for (int i = tid; i < PDIM; i += 256) s += __expf(bij[i*10 + o] - m);
    red[tid] = s; __syncthreads();
    for (int st = 128; st > 0; st >>= 1) {
        if (tid < st) red[tid] += red[tid+st];
        __syncthreads();
    }
    if (tid == 0) { cstat[o] = m; cstat[16 + o] = red[0]; }
}

// ---------------- K5: pass A — partial s_j, u_hat recomputed inline ----------------
__global__ __launch_bounds__(256) void k_route_sj(const float* __restrict__ Wd,
        const float* __restrict__ xq, const float* __restrict__ bij,
        const float* __restrict__ cstat, float* __restrict__ sjp) {
    int tid = threadIdx.x;
    int bq = tid & 31, g = tid >> 5;
    int os0 = g*20;
    int o0 = os0 >> 4, o1 = o0 + 1;      // each 20-wide os range spans exactly 2 o's
    float cm0 = cstat[o0], cm1 = cstat[o1];
    float rd0 = 1.f / cstat[16+o0], rd1 = 1.f / cstat[16+o1];
    float acc[20];
    #pragma unroll
    for (int i = 0; i < 20; ++i) acc[i] = 0.f;
    int p0 = blockIdx.x * 64;
    for (int p = p0; p < p0+64; ++p) {
        const float4* xr = (const float4*)(xq + (size_t)p*256 + bq*8);
        float4 xa = xr[0], xb = xr[1];
        float c0 = __expf(bij[p*10+o0] - cm0) * rd0;
        float c1 = __expf(bij[p*10+o1] - cm1) * rd1;
        const float4* wr = (const float4*)(Wd + (size_t)p*1280 + os0*8);
        #pragma unroll
        for (int i = 0; i < 20; ++i) {
            float4 w0 = wr[i*2], w1 = wr[i*2+1];
            float uh = w0.x*xa.x + w0.y*xa.y + w0.z*xa.z + w0.w*xa.w
                     + w1.x*xb.x + w1.y*xb.y + w1.z*xb.z + w1.w*xb.w;
            int oi = (os0 + i) >> 4;
            acc[i] += (oi == o0 ? c0 : c1) * uh;
        }
    }
    float* outp = sjp + (size_t)blockIdx.x*5120 + bq*OSD + os0;
    #pragma unroll
    for (int i = 0; i < 20; ++i) outp[i] = acc[i];
}

// ---------------- K6a: reduce partials -> s_j ----------------
__global__ void k_reduce_sj(const float* __restrict__ sjp, float* __restrict__ sj) {
    int e = blockIdx.x*128 + threadIdx.x;
    float s = 0.f;
    for (int k = 0; k < NBLK_A; ++k) s += sjp[(size_t)k*5120 + e];
    sj[e] = s;
}

// ---------------- K6b: v = squash(s_j over O axis); optionally write d_out ----------------
__global__ void k_squash_v(const float* __restrict__ sj, float* __restrict__ v,
                           float* __restrict__ dout, int writeOut) {
    __shared__ float ss[5120];
    int tid = threadIdx.x;
    for (int i = tid; i < 5120; i += 512) ss[i] = sj[i];
    __syncthreads();
    int b = tid >> 4, s = tid & 15;      // 512 = 32*16
    float msq = 0.f;
    #pragma unroll
    for (int o = 0; o < 10; ++o) { float t = ss[b*160 + o*16 + s]; msq += t*t; }
    float sc = sqrtf(msq) / (1.f + msq);
    #pragma unroll
    for (int o = 0; o < 10; ++o) {
        float val = ss[b*160 + o*16 + s] * sc;
        v[b*160 + o*16 + s] = val;
        if (writeOut) dout[b*160 + o*16 + s] = val;
    }
}

// ---------------- K7: pass B — b_ij += mean_b sum_s u_hat*v ----------------
__global__ __launch_bounds__(320) void k_route_bij(const float* __restrict__ Wd,
        const float* __restrict__ xq, const float* __restrict__ v,
        float* __restrict__ bij) {
    __shared__ float sv[5120];
    __shared__ float sxq[32*260];        // padded rows: 4-way worst on b128, 16B aligned
    int tid = threadIdx.x;
    int p0 = blockIdx.x*32;
    for (int e = tid; e < 5120; e += 320) sv[e] = v[e];
    for (int e = tid; e < 8192; e += 320) {
        int pl = e >> 8, bu = e & 255;
        sxq[pl*260 + bu] = xq[(size_t)(p0+pl)*256 + bu];
    }
    __syncthreads();
    int pl = tid / 10, o = tid - pl*10;  // 320 = 32p x 10o
    int p = p0 + pl;
    const float4* wr = (const float4*)(Wd + (size_t)p*1280 + o*128);
    float4 wreg[32];                      // W[p][o][s=0..15][u=0..7], static-indexed
    #pragma unroll
    for (int i = 0; i < 32; ++i) wreg[i] = wr[i];
    float acc = 0.f;
    for (int bq = 0; bq < 32; ++bq) {
        float4 x0 = *(const float4*)&sxq[pl*260 + bq*8];
        float4 x1 = *(const float4*)&sxq[pl*260 + bq*8 + 4];
        #pragma unroll
        for (int sg = 0; sg < 4; ++sg) {
            float4 vs = *(const float4*)&sv[bq*160 + o*16 + sg*4];
            float vsv[4] = {vs.x, vs.y, vs.z, vs.w};
            #pragma unroll
            for (int s4 = 0; s4 < 4; ++s4) {
                int s = sg*4 + s4;
                float4 w0 = wreg[s*2], w1 = wreg[s*2+1];
                float uh = w0.x*x0.x + w0.y*x0.y + w0.z*x0.z + w0.w*x0.w
                         + w1.x*x1.x + w1.y*x1.y + w1.z*x1.z + w1.w*x1.w;
                acc += uh * vsv[s4];
            }
        }
    }
    bij[p*10 + o] += acc * (1.f/32.f);
}

extern "C" void kernel_launch(void* const* d_in, const int* in_sizes, int n_in,
                              void* d_out, int out_size, void* d_ws, size_t ws_size,
                              hipStream_t stream) {
    const float* x   = (const float*)d_in[0];
    const float* c1w = (const float*)d_in[1];
    const float* c1b = (const float*)d_in[2];
    const float* pw  = (const float*)d_in[3];
    const float* pb  = (const float*)d_in[4];
    const float* Wd  = (const float*)d_in[5];
    float* out = (float*)d_out;

    // workspace carve-up (floats); total ~77.8 MB
    float* ws    = (float*)d_ws;
    float* h     = ws;                    // 32*256*784   = 6,422,528
    float* Wk    = h   + 6422528;         // 81*256*256   = 5,308,416
    float* up    = Wk  + 5308416;         // 32*8*12800   = 3,276,800
    float* xq    = up  + 3276800;         // 12800*256    = 3,276,800
    float* scl   = xq  + 3276800;         // 256
    float* bij   = scl + 256;             // 12800*10     = 128,000
    float* cstat = bij + 128000;          // 32 (max[10] @0, den[10] @16)
    float* sjp   = cstat + 32;            // 200*5120     = 1,024,000
    float* sj    = sjp + 1024000;         // 5120
    float* vv    = sj  + 5120;            // 5120

    hipMemsetAsync(bij, 0, 128000*sizeof(float), stream);

    k_transpose_w<<<dim3(8,8,9), 256, 0, stream>>>(pw, Wk);
    k_conv1<<<dim3(32,16), 256, 0, stream>>>(x, c1w, c1b, h);
    k_prim_gemm<<<dim3(100,4), 256, 0, stream>>>(h, Wk, pb, up);
    k_scale<<<256, 256, 0, stream>>>(up, scl);
    k_xq<<<400, 256, 0, stream>>>(up, scl, xq);

    for (int it = 0; it < 3; ++it) {
        k_softmax_stats<<<10, 256, 0, stream>>>(bij, cstat);
        k_route_sj<<<NBLK_A, 256, 0, stream>>>(Wd, xq, bij, cstat, sjp);
        k_reduce_sj<<<40, 128, 0, stream>>>(sjp, sj);
        k_squash_v<<<1, 512, 0, stream>>>(sj, vv, out, it == 2 ? 1 : 0);
        if (it < 2)
            k_route_bij<<<400, 320, 0, stream>>>(Wd, xq, vv, bij);
    }
}

// Round 2
// 1581.581 us; speedup vs baseline: 1.9398x; 1.9398x over previous
//
#include <hip/hip_runtime.h>
#include <math.h>

// ---- problem constants ----
static constexpr int PDIM = 12800;      // 32ch*400
static constexpr int OSD  = 160;        // 10*16
static constexpr int NBLK_A = 200;      // pass-A blocks (64 p each)

typedef short  bfv8  __attribute__((ext_vector_type(8)));
typedef unsigned short usv8 __attribute__((ext_vector_type(8)));
typedef float  f32x4 __attribute__((ext_vector_type(4)));

__device__ __forceinline__ unsigned short f2bf(float f) {
    union { float f; unsigned u; } c; c.f = f;
    unsigned u = c.u;
    unsigned r = (u + 0x7FFFu + ((u >> 16) & 1u)) >> 16;
    return (unsigned short)r;
}
__device__ __forceinline__ float bf2f(unsigned short h) {
    union { unsigned u; float f; } c; c.u = ((unsigned)h) << 16;
    return c.f;
}
__device__ __forceinline__ void gload16(const void* g, void* l) {
    __builtin_amdgcn_global_load_lds(
        (const __attribute__((address_space(1))) void*)g,
        (__attribute__((address_space(3))) void*)l, 16, 0, 0);
}

// ---------------- K0: prim_w[co][ci][81] -> Wkf[k][co][ci] fp32 ----------------
__global__ void k_prep_w(const float* __restrict__ w, float* __restrict__ Wkf) {
    int co = blockIdx.x, ci = threadIdx.x;
    const float* src = w + ((size_t)co*256 + ci)*81;
    for (int k = 0; k < 81; ++k)
        Wkf[(size_t)k*65536 + co*256 + ci] = src[k];
}

// ---------------- K1: conv1 + bias + relu -> ht planes [b][pos][co] bf16x3 ----------------
__global__ void k_conv1(const float* __restrict__ x, const float* __restrict__ w,
                        const float* __restrict__ bias,
                        unsigned short* __restrict__ ht1, unsigned short* __restrict__ ht2,
                        unsigned short* __restrict__ ht3) {
    __shared__ float sx[1296];
    __shared__ float sw[1296];
    int b = blockIdx.x, cog = blockIdx.y;
    int tid = threadIdx.x;
    for (int i = tid; i < 1296; i += 256) {
        sx[i] = x[b*1296 + i];
        sw[i] = w[cog*1296 + i];
    }
    __syncthreads();
    for (int pos = tid; pos < 784; pos += 256) {
        int y = pos / 28, xx = pos - y*28;
        float acc[16];
        #pragma unroll
        for (int c = 0; c < 16; ++c) acc[c] = 0.f;
        for (int ky = 0; ky < 9; ++ky) {
            #pragma unroll
            for (int kx = 0; kx < 9; ++kx) {
                float xv = sx[(y+ky)*36 + xx + kx];
                #pragma unroll
                for (int c = 0; c < 16; ++c)
                    acc[c] += xv * sw[c*81 + ky*9 + kx];
            }
        }
        #pragma unroll
        for (int c = 0; c < 16; ++c) {
            float r = acc[c] + bias[cog*16 + c];
            r = r > 0.f ? r : 0.f;
            unsigned short h1 = f2bf(r);  float q1 = r - bf2f(h1);
            unsigned short h2 = f2bf(q1); float q2 = q1 - bf2f(h2);
            unsigned short h3 = f2bf(q2);
            size_t o = ((size_t)b*784 + pos)*256 + cog*16 + c;
            ht1[o] = h1; ht2[o] = h2; ht3[o] = h3;
        }
    }
}

// ---------------- K2: primary conv as 81 shifted GEMMs, bf16 3-plane split MFMA ----------------
// C[co][n] = sum_{k,ci} Wkf[k][co][ci] * ht[b(n)][sp(n)+spk][ci]
// BM=128 BN=256 BK=32, 512 thr (8 waves 2x4, 64x64/wave), dbuf 144KB LDS, ksplit=8 atomics.
__global__ __launch_bounds__(512, 2) void k_prim_mfma(
        const unsigned short* __restrict__ ht1, const unsigned short* __restrict__ ht2,
        const unsigned short* __restrict__ ht3, const float* __restrict__ Wkf,
        float* __restrict__ Clin) {
    // per-buffer halfs: A1 0, A2 4096, A3 8192, B1 12288, B2 20480, B3 28672 (36864 total)
    __shared__ unsigned short lds[73728];
    const int t   = threadIdx.x;
    const int n0  = blockIdx.x * 256;
    const int co0 = blockIdx.y * 128;
    const int z   = blockIdx.z;
    const int klo = (z*81) >> 3, khi = ((z+1)*81) >> 3;
    const int NSTEP = (khi - klo) * 8;

    // staging precompute
    const int srow = t >> 2, slot = t & 3;
    const int g = slot ^ ((srow >> 1) & 3);           // source-pre-swizzle k-group
    const size_t aSrcOff = (size_t)(co0 + srow)*256 + slot*8;
    const int aDstOff = srow*32 + g*8;
    int n1 = n0 + srow, n2 = n1 + 128;
    int b1 = n1/400, rr1 = n1 - b1*400, y1 = rr1/20, x1 = rr1 - y1*20;
    int b2 = n2/400, rr2 = n2 - b2*400, y2 = rr2/20, x2 = rr2 - y2*20;
    const size_t bOff1 = ((size_t)b1*784 + y1*28 + x1)*256 + g*8;
    const size_t bOff2 = ((size_t)b2*784 + y2*28 + x2)*256 + g*8;

    // compute-side precompute
    const int l = t & 63, w8 = t >> 6;
    const int wm = w8 >> 2, wn = w8 & 3;
    const int lm = l & 15, lk = l >> 4;
    int aoff[4], boff[4];
    #pragma unroll
    for (int i = 0; i < 4; ++i) {
        int ra = wm*64 + i*16 + lm;
        aoff[i] = ra*32 + ((lk ^ ((ra>>1)&3))*8);
        int rb = wn*64 + i*16 + lm;
        boff[i] = rb*32 + ((lk ^ ((rb>>1)&3))*8);
    }

    f32x4 acc[4][4];
    #pragma unroll
    for (int i = 0; i < 4; ++i)
        #pragma unroll
        for (int j = 0; j < 4; ++j) { acc[i][j][0]=0.f; acc[i][j][1]=0.f; acc[i][j][2]=0.f; acc[i][j][3]=0.f; }

    f32x4 av0, av1;

#define ALOAD(KK, CC) { const float* ap = Wkf + (size_t)(KK)*65536 + (CC)*32 + aSrcOff; \
        av0 = *(const f32x4*)ap; av1 = *(const f32x4*)(ap + 4); }

#define BGLOAD(LB, SPK, CC) { size_t so = (size_t)(SPK)*256 + (CC)*32; \
        gload16(ht1 + bOff1 + so, (LB) + 12288 + t*8); \
        gload16(ht1 + bOff2 + so, (LB) + 16384 + t*8); \
        gload16(ht2 + bOff1 + so, (LB) + 20480 + t*8); \
        gload16(ht2 + bOff2 + so, (LB) + 24576 + t*8); \
        gload16(ht3 + bOff1 + so, (LB) + 28672 + t*8); \
        gload16(ht3 + bOff2 + so, (LB) + 32768 + t*8); }

#define AWRITE(LB) { usv8 u1, u2, u3; \
        _Pragma("unroll") \
        for (int j = 0; j < 8; ++j) { \
            float v = (j < 4) ? av0[j] : av1[j-4]; \
            unsigned short h1 = f2bf(v);  float q1 = v - bf2f(h1); \
            unsigned short h2 = f2bf(q1); float q2 = q1 - bf2f(h2); \
            unsigned short h3 = f2bf(q2); \
            u1[j] = h1; u2[j] = h2; u3[j] = h3; } \
        *(usv8*)((LB) + aDstOff)        = u1; \
        *(usv8*)((LB) + 4096 + aDstOff) = u2; \
        *(usv8*)((LB) + 8192 + aDstOff) = u3; }

    // prologue: stage step 0 into buf0
    {
        int k0 = klo;
        int spk0 = (k0/9)*28 + (k0 - (k0/9)*9);
        ALOAD(k0, 0);
        BGLOAD(lds, spk0, 0);
        AWRITE(lds);
    }
    __syncthreads();

    for (int s = 0; s < NSTEP; ++s) {
        const int d = s & 1;
        unsigned short* Lnext = lds + (d ? 0 : 36864);
        const unsigned short* L = lds + (d ? 36864 : 0);
        const bool pf = (s + 1) < NSTEP;
        if (pf) {
            int s1 = s + 1;
            int k1 = klo + (s1 >> 3), cc1 = s1 & 7;
            int spk1 = (k1/9)*28 + (k1 - (k1/9)*9);
            ALOAD(k1, cc1);
            BGLOAD(Lnext, spk1, cc1);
        }
        // compute on buffer L
        {
            bfv8 a1[4], a2[4], a3[4];
            #pragma unroll
            for (int mi = 0; mi < 4; ++mi) {
                a1[mi] = *(const bfv8*)(L + aoff[mi]);
                a2[mi] = *(const bfv8*)(L + 4096 + aoff[mi]);
                a3[mi] = *(const bfv8*)(L + 8192 + aoff[mi]);
            }
            #pragma unroll
            for (int nj = 0; nj < 4; ++nj) {
                bfv8 q1 = *(const bfv8*)(L + 12288 + boff[nj]);
                bfv8 q2 = *(const bfv8*)(L + 20480 + boff[nj]);
                bfv8 q3 = *(const bfv8*)(L + 28672 + boff[nj]);
                #pragma unroll
                for (int mi = 0; mi < 4; ++mi) {
                    f32x4 c = acc[mi][nj];
                    c = __builtin_amdgcn_mfma_f32_16x16x32_bf16(a1[mi], q1, c, 0, 0, 0);
                    c = __builtin_amdgcn_mfma_f32_16x16x32_bf16(a1[mi], q2, c, 0, 0, 0);
                    c = __builtin_amdgcn_mfma_f32_16x16x32_bf16(a2[mi], q1, c, 0, 0, 0);
                    c = __builtin_amdgcn_mfma_f32_16x16x32_bf16(a1[mi], q3, c, 0, 0, 0);
                    c = __builtin_amdgcn_mfma_f32_16x16x32_bf16(a2[mi], q2, c, 0, 0, 0);
                    c = __builtin_amdgcn_mfma_f32_16x16x32_bf16(a3[mi], q1, c, 0, 0, 0);
                    acc[mi][nj] = c;
                }
            }
        }
        if (pf) AWRITE(Lnext);
        __syncthreads();
    }

    // epilogue: atomic accumulate into Clin[co][n]
    #pragma unroll
    for (int mi = 0; mi < 4; ++mi) {
        #pragma unroll
        for (int nj = 0; nj < 4; ++nj) {
            int nn = n0 + wn*64 + nj*16 + lm;
            #pragma unroll
            for (int r = 0; r < 4; ++r) {
                int co = co0 + wm*64 + mi*16 + lk*4 + r;
                atomicAdd(&Clin[(size_t)co*12800 + nn], acc[mi][nj][r]);
            }
        }
    }
#undef ALOAD
#undef BGLOAD
#undef AWRITE
}

// ---------------- K2b: Clin + bias -> up[b][unit][ch*400+rr] ----------------
__global__ void k_finalize_up(const float* __restrict__ Clin, const float* __restrict__ bias,
                              float* __restrict__ up) {
    int e = blockIdx.x*256 + threadIdx.x;
    int co = e / 12800, n = e - co*12800;
    int unit = co >> 5, ch = co & 31;
    int bn = n / 400, rr = n - bn*400;
    up[(size_t)(bn*8 + unit)*PDIM + ch*400 + rr] = Clin[e] + bias[co];
}

// ---------------- K3a: squash scale per (b,unit) ----------------
__global__ void k_scale(const float* __restrict__ up, float* __restrict__ scl) {
    __shared__ float red[256];
    int bu = blockIdx.x, tid = threadIdx.x;
    const float* base = up + (size_t)bu*PDIM;
    float s = 0.f;
    for (int i = tid; i < PDIM; i += 256) { float v = base[i]; s += v*v; }
    red[tid] = s; __syncthreads();
    for (int st = 128; st > 0; st >>= 1) {
        if (tid < st) red[tid] += red[tid+st];
        __syncthreads();
    }
    if (tid == 0) {
        float msq = red[0];
        scl[bu] = sqrtf(msq) / (1.f + msq);
    }
}

// ---------------- K3b: xq[p][b*8+u] = up[b][u][p] * scl[b][u] ----------------
__global__ void k_xq(const float* __restrict__ up, const float* __restrict__ scl,
                     float* __restrict__ xq) {
    __shared__ float sT[32][257];
    __shared__ float sS[256];
    int p0 = blockIdx.x*32, tid = threadIdx.x;
    sS[tid] = scl[tid];
    __syncthreads();
    for (int r = 0; r < 32; ++r) {
        int e = r*256 + tid;
        int bu = e >> 5, pi = e & 31;
        sT[pi][bu] = up[(size_t)bu*PDIM + p0 + pi] * sS[bu];
    }
    __syncthreads();
    for (int r = 0; r < 32; ++r)
        xq[(size_t)(p0+r)*256 + tid] = sT[r][tid];
}

// ---------------- K4: softmax-over-P stats per o ----------------
__global__ void k_softmax_stats(const float* __restrict__ bij, float* __restrict__ cstat) {
    __shared__ float red[256];
    int o = blockIdx.x, tid = threadIdx.x;
    float m = -1e30f;
    for (int i = tid; i < PDIM; i += 256) m = fmaxf(m, bij[i*10 + o]);
    red[tid] = m; __syncthreads();
    for (int st = 128; st > 0; st >>= 1) {
        if (tid < st) red[tid] = fmaxf(red[tid], red[tid+st]);
        __syncthreads();
    }
    m = red[0]; __syncthreads();
    float s = 0.f;
    for (int i = tid; i < PDIM; i += 256) s += __expf(bij[i*10 + o] - m);
    red[tid] = s; __syncthreads();
    for (int st = 128; st > 0; st >>= 1) {
        if (tid < st) red[tid] += red[tid+st];
        __syncthreads();
    }
    if (tid == 0) { cstat[o] = m; cstat[16 + o] = red[0]; }
}

// ---------------- K5: pass A — partial s_j, u_hat recomputed inline ----------------
__global__ __launch_bounds__(256) void k_route_sj(const float* __restrict__ Wd,
        const float* __restrict__ xq, const float* __restrict__ bij,
        const float* __restrict__ cstat, float* __restrict__ sjp) {
    int tid = threadIdx.x;
    int bq = tid & 31, g = tid >> 5;
    int os0 = g*20;
    int o0 = os0 >> 4, o1 = o0 + 1;
    float cm0 = cstat[o0], cm1 = cstat[o1];
    float rd0 = 1.f / cstat[16+o0], rd1 = 1.f / cstat[16+o1];
    float acc[20];
    #pragma unroll
    for (int i = 0; i < 20; ++i) acc[i] = 0.f;
    int p0 = blockIdx.x * 64;
    for (int p = p0; p < p0+64; ++p) {
        const float4* xr = (const float4*)(xq + (size_t)p*256 + bq*8);
        float4 xa = xr[0], xb = xr[1];
        float c0 = __expf(bij[p*10+o0] - cm0) * rd0;
        float c1 = __expf(bij[p*10+o1] - cm1) * rd1;
        const float4* wr = (const float4*)(Wd + (size_t)p*1280 + os0*8);
        #pragma unroll
        for (int i = 0; i < 20; ++i) {
            float4 w0 = wr[i*2], w1 = wr[i*2+1];
            float uh = w0.x*xa.x + w0.y*xa.y + w0.z*xa.z + w0.w*xa.w
                     + w1.x*xb.x + w1.y*xb.y + w1.z*xb.z + w1.w*xb.w;
            int oi = (os0 + i) >> 4;
            acc[i] += (oi == o0 ? c0 : c1) * uh;
        }
    }
    float* outp = sjp + (size_t)blockIdx.x*5120 + bq*OSD + os0;
    #pragma unroll
    for (int i = 0; i < 20; ++i) outp[i] = acc[i];
}

// ---------------- K6a: reduce partials -> s_j ----------------
__global__ void k_reduce_sj(const float* __restrict__ sjp, float* __restrict__ sj) {
    int e = blockIdx.x*128 + threadIdx.x;
    float s = 0.f;
    for (int k = 0; k < NBLK_A; ++k) s += sjp[(size_t)k*5120 + e];
    sj[e] = s;
}

// ---------------- K6b: v = squash(s_j over O axis); optionally write d_out ----------------
__global__ void k_squash_v(const float* __restrict__ sj, float* __restrict__ v,
                           float* __restrict__ dout, int writeOut) {
    __shared__ float ss[5120];
    int tid = threadIdx.x;
    for (int i = tid; i < 5120; i += 512) ss[i] = sj[i];
    __syncthreads();
    int b = tid >> 4, s = tid & 15;
    float msq = 0.f;
    #pragma unroll
    for (int o = 0; o < 10; ++o) { float tq = ss[b*160 + o*16 + s]; msq += tq*tq; }
    float sc = sqrtf(msq) / (1.f + msq);
    #pragma unroll
    for (int o = 0; o < 10; ++o) {
        float val = ss[b*160 + o*16 + s] * sc;
        v[b*160 + o*16 + s] = val;
        if (writeOut) dout[b*160 + o*16 + s] = val;
    }
}

// ---------------- K7: pass B — b_ij += mean_b sum_s u_hat*v ----------------
__global__ __launch_bounds__(320) void k_route_bij(const float* __restrict__ Wd,
        const float* __restrict__ xq, const float* __restrict__ v,
        float* __restrict__ bij) {
    __shared__ float sv[5120];
    __shared__ float sxq[32*260];
    int tid = threadIdx.x;
    int p0 = blockIdx.x*32;
    for (int e = tid; e < 5120; e += 320) sv[e] = v[e];
    for (int e = tid; e < 8192; e += 320) {
        int pl = e >> 8, bu = e & 255;
        sxq[pl*260 + bu] = xq[(size_t)(p0+pl)*256 + bu];
    }
    __syncthreads();
    int pl = tid / 10, o = tid - pl*10;
    int p = p0 + pl;
    const float4* wr = (const float4*)(Wd + (size_t)p*1280 + o*128);
    float4 wreg[32];
    #pragma unroll
    for (int i = 0; i < 32; ++i) wreg[i] = wr[i];
    float acc = 0.f;
    for (int bq = 0; bq < 32; ++bq) {
        float4 x0 = *(const float4*)&sxq[pl*260 + bq*8];
        float4 x1 = *(const float4*)&sxq[pl*260 + bq*8 + 4];
        #pragma unroll
        for (int sg = 0; sg < 4; ++sg) {
            float4 vs = *(const float4*)&sv[bq*160 + o*16 + sg*4];
            float vsv[4] = {vs.x, vs.y, vs.z, vs.w};
            #pragma unroll
            for (int s4 = 0; s4 < 4; ++s4) {
                int s = sg*4 + s4;
                float4 w0 = wreg[s*2], w1 = wreg[s*2+1];
                float uh = w0.x*x0.x + w0.y*x0.y + w0.z*x0.z + w0.w*x0.w
                         + w1.x*x1.x + w1.y*x1.y + w1.z*x1.z + w1.w*x1.w;
                acc += uh * vsv[s4];
            }
        }
    }
    bij[p*10 + o] += acc * (1.f/32.f);
}

extern "C" void kernel_launch(void* const* d_in, const int* in_sizes, int n_in,
                              void* d_out, int out_size, void* d_ws, size_t ws_size,
                              hipStream_t stream) {
    const float* x   = (const float*)d_in[0];
    const float* c1w = (const float*)d_in[1];
    const float* c1b = (const float*)d_in[2];
    const float* pw  = (const float*)d_in[3];
    const float* pb  = (const float*)d_in[4];
    const float* Wd  = (const float*)d_in[5];
    float* out = (float*)d_out;

    // workspace map (bytes): total 73,430,144
    char* wsb = (char*)d_ws;
    unsigned short* ht1 = (unsigned short*)(wsb);              // 12,845,056
    unsigned short* ht2 = (unsigned short*)(wsb + 12845056);   // 12,845,056
    unsigned short* ht3 = (unsigned short*)(wsb + 25690112);   // 12,845,056
    float* Wkf  = (float*)(wsb + 38535168);                    // 21,233,664
    float* Clin = (float*)(wsb + 59768832);                    // 13,107,200
    char* tailb = wsb + 72876032;
    float* bij   = (float*)tailb;                              // 512,000
    float* cstat = bij + 128000;                               // 128 B (32 f)
    float* sj    = cstat + 32;                                 // 20,480
    float* vv    = sj + 5120;                                  // 20,480
    float* scl   = vv + 5120;                                  // 1,024
    // aliases over dead regions:
    float* up  = (float*)(wsb + 38535168);   // over Wkf (dead after GEMM)
    float* xq  = (float*)(wsb);              // over ht planes (dead after GEMM)
    float* sjp = (float*)(wsb + 59768832);   // over Clin (dead after finalize)

    hipMemsetAsync(Clin, 0, 13107200, stream);
    hipMemsetAsync(bij, 0, 512000, stream);

    k_prep_w<<<256, 256, 0, stream>>>(pw, Wkf);
    k_conv1<<<dim3(32,16), 256, 0, stream>>>(x, c1w, c1b, ht1, ht2, ht3);
    k_prim_mfma<<<dim3(50,2,8), 512, 0, stream>>>(ht1, ht2, ht3, Wkf, Clin);
    k_finalize_up<<<12800, 256, 0, stream>>>(Clin, pb, up);
    k_scale<<<256, 256, 0, stream>>>(up, scl);
    k_xq<<<400, 256, 0, stream>>>(up, scl, xq);

    for (int it = 0; it < 3; ++it) {
        k_softmax_stats<<<10, 256, 0, stream>>>(bij, cstat);
        k_route_sj<<<NBLK_A, 256, 0, stream>>>(Wd, xq, bij, cstat, sjp);
        k_reduce_sj<<<40, 128, 0, stream>>>(sjp, sj);
        k_squash_v<<<1, 512, 0, stream>>>(sj, vv, out, it == 2 ? 1 : 0);
        if (it < 2)
            k_route_bij<<<400, 320, 0, stream>>>(Wd, xq, vv, bij);
    }
}

// Round 3
// 1276.613 us; speedup vs baseline: 2.4032x; 1.2389x over previous
//
#include <hip/hip_runtime.h>
#include <math.h>

// ---- problem constants ----
static constexpr int PDIM = 12800;      // 32ch*400
static constexpr int OSD  = 160;        // 10*16
static constexpr int NBLK_A = 200;      // pass-A blocks (64 p each)

typedef _Float16 hv8  __attribute__((ext_vector_type(8)));
typedef float    f32x4 __attribute__((ext_vector_type(4)));

__device__ __forceinline__ void gload16(const void* g, void* l) {
    __builtin_amdgcn_global_load_lds(
        (const __attribute__((address_space(1))) void*)g,
        (__attribute__((address_space(3))) void*)l, 16, 0, 0);
}

// ---------------- K0: prim_w[co][ci][81] -> Wkf[k][co][ci] fp32 ----------------
__global__ void k_prep_w(const float* __restrict__ w, float* __restrict__ Wkf) {
    int co = blockIdx.x, ci = threadIdx.x;
    const float* src = w + ((size_t)co*256 + ci)*81;
    for (int k = 0; k < 81; ++k)
        Wkf[(size_t)k*65536 + co*256 + ci] = src[k];
}

// ---------------- K1: conv1 + bias + relu -> ht planes [b][pos][co] fp16 x2 ----------------
__global__ void k_conv1(const float* __restrict__ x, const float* __restrict__ w,
                        const float* __restrict__ bias,
                        _Float16* __restrict__ ht1, _Float16* __restrict__ ht2) {
    __shared__ float sx[1296];
    __shared__ float sw[1296];
    int b = blockIdx.x, cog = blockIdx.y;
    int tid = threadIdx.x;
    for (int i = tid; i < 1296; i += 256) {
        sx[i] = x[b*1296 + i];
        sw[i] = w[cog*1296 + i];
    }
    __syncthreads();
    for (int pos = tid; pos < 784; pos += 256) {
        int y = pos / 28, xx = pos - y*28;
        float acc[16];
        #pragma unroll
        for (int c = 0; c < 16; ++c) acc[c] = 0.f;
        for (int ky = 0; ky < 9; ++ky) {
            #pragma unroll
            for (int kx = 0; kx < 9; ++kx) {
                float xv = sx[(y+ky)*36 + xx + kx];
                #pragma unroll
                for (int c = 0; c < 16; ++c)
                    acc[c] += xv * sw[c*81 + ky*9 + kx];
            }
        }
        #pragma unroll
        for (int c = 0; c < 16; ++c) {
            float r = acc[c] + bias[cog*16 + c];
            r = r > 0.f ? r : 0.f;
            _Float16 h1 = (_Float16)r;
            float q1 = r - (float)h1;
            _Float16 h2 = (_Float16)q1;
            size_t o = ((size_t)b*784 + pos)*256 + cog*16 + c;
            ht1[o] = h1; ht2[o] = h2;
        }
    }
}

// ---------------- K2: primary conv as 81 shifted GEMMs, fp16 2-plane split MFMA ----------------
// C[co][n] = sum_{k,ci} Wkf[k][co][ci] * ht[b(n)][sp(n)+spk][ci]
// BM=128 BN=256 BK=32, 512 thr (8 waves 2x4, 64x64/wave), dbuf 96KB LDS, ksplit=8 atomics.
// products kept: a1b1 + a1b2 + a2b1 (dropped a2b2 ~ 2^-22 rel, below fp32 accum noise)
__global__ __launch_bounds__(512, 2) void k_prim_mfma(
        const _Float16* __restrict__ ht1, const _Float16* __restrict__ ht2,
        const float* __restrict__ Wkf, float* __restrict__ Clin) {
    // per-buffer (elems): A1 @0 (4096), A2 @4096, B1 @8192 (8192), B2 @16384; BUF=24576
    __shared__ _Float16 lds[49152];
    const int t   = threadIdx.x;
    const int n0  = blockIdx.x * 256;
    const int co0 = blockIdx.y * 128;
    const int z   = blockIdx.z;
    const int klo = (z*81) >> 3, khi = ((z+1)*81) >> 3;
    const int NSTEP = (khi - klo) * 8;

    // staging precompute (source-pre-swizzled k-group, LDS dest lane-linear)
    const int srow = t >> 2, slot = t & 3;
    const int g = slot ^ ((srow >> 1) & 3);
    const size_t aSrcOff = (size_t)(co0 + srow)*256 + slot*8;
    const int aDstOff = srow*32 + g*8;
    int n1 = n0 + srow, n2 = n1 + 128;
    int b1 = n1/400, rr1 = n1 - b1*400, y1 = rr1/20, x1 = rr1 - y1*20;
    int b2 = n2/400, rr2 = n2 - b2*400, y2 = rr2/20, x2 = rr2 - y2*20;
    const size_t bOff1 = ((size_t)b1*784 + y1*28 + x1)*256 + g*8;
    const size_t bOff2 = ((size_t)b2*784 + y2*28 + x2)*256 + g*8;

    // compute-side precompute
    const int l = t & 63, w8 = t >> 6;
    const int wm = w8 >> 2, wn = w8 & 3;
    const int lm = l & 15, lk = l >> 4;
    int aoff[4], boff[4];
    #pragma unroll
    for (int i = 0; i < 4; ++i) {
        int ra = wm*64 + i*16 + lm;
        aoff[i] = ra*32 + ((lk ^ ((ra>>1)&3))*8);
        int rb = wn*64 + i*16 + lm;
        boff[i] = 8192 + rb*32 + ((lk ^ ((rb>>1)&3))*8);
    }

    f32x4 acc[4][4];
    #pragma unroll
    for (int i = 0; i < 4; ++i)
        #pragma unroll
        for (int j = 0; j < 4; ++j) { acc[i][j][0]=0.f; acc[i][j][1]=0.f; acc[i][j][2]=0.f; acc[i][j][3]=0.f; }

    f32x4 av0, av1;

#define ALOAD(KK, CC) { const float* ap = Wkf + (size_t)(KK)*65536 + (CC)*32 + aSrcOff; \
        av0 = *(const f32x4*)ap; av1 = *(const f32x4*)(ap + 4); }

#define BGLOAD(LB, SPK, CC) { size_t so = (size_t)(SPK)*256 + (CC)*32; \
        gload16(ht1 + bOff1 + so, (LB) + 8192  + t*8); \
        gload16(ht1 + bOff2 + so, (LB) + 12288 + t*8); \
        gload16(ht2 + bOff1 + so, (LB) + 16384 + t*8); \
        gload16(ht2 + bOff2 + so, (LB) + 20480 + t*8); }

#define AWRITE(LB) { hv8 u1, u2; \
        _Pragma("unroll") \
        for (int j = 0; j < 8; ++j) { \
            float v_ = (j < 4) ? av0[j] : av1[j-4]; \
            _Float16 h1 = (_Float16)v_; \
            float q_ = v_ - (float)h1; \
            _Float16 h2 = (_Float16)q_; \
            u1[j] = h1; u2[j] = h2; } \
        *(hv8*)((LB) + aDstOff)        = u1; \
        *(hv8*)((LB) + 4096 + aDstOff) = u2; }

    // prologue: stage step 0 into buf0
    {
        int k0 = klo;
        int spk0 = (k0/9)*28 + (k0 - (k0/9)*9);
        ALOAD(k0, 0);
        BGLOAD(lds, spk0, 0);
        AWRITE(lds);
    }
    __syncthreads();

    for (int s = 0; s < NSTEP; ++s) {
        const int d = s & 1;
        _Float16* Lnext = lds + (d ? 0 : 24576);
        const _Float16* L = lds + (d ? 24576 : 0);
        const bool pf = (s + 1) < NSTEP;
        if (pf) {
            int s1 = s + 1;
            int k1 = klo + (s1 >> 3), cc1 = s1 & 7;
            int spk1 = (k1/9)*28 + (k1 - (k1/9)*9);
            ALOAD(k1, cc1);
            BGLOAD(Lnext, spk1, cc1);
        }
        // compute on buffer L
        {
            hv8 a1[4], a2[4];
            #pragma unroll
            for (int mi = 0; mi < 4; ++mi) {
                a1[mi] = *(const hv8*)(L + aoff[mi]);
                a2[mi] = *(const hv8*)(L + 4096 + aoff[mi]);
            }
            #pragma unroll
            for (int nj = 0; nj < 4; ++nj) {
                hv8 q1 = *(const hv8*)(L + boff[nj]);
                hv8 q2 = *(const hv8*)(L + 8192 + boff[nj]);
                #pragma unroll
                for (int mi = 0; mi < 4; ++mi) {
                    f32x4 c = acc[mi][nj];
                    c = __builtin_amdgcn_mfma_f32_16x16x32_f16(a1[mi], q1, c, 0, 0, 0);
                    c = __builtin_amdgcn_mfma_f32_16x16x32_f16(a1[mi], q2, c, 0, 0, 0);
                    c = __builtin_amdgcn_mfma_f32_16x16x32_f16(a2[mi], q1, c, 0, 0, 0);
                    acc[mi][nj] = c;
                }
            }
        }
        if (pf) AWRITE(Lnext);
        __syncthreads();
    }

    // epilogue: atomic accumulate into Clin[co][n]
    #pragma unroll
    for (int mi = 0; mi < 4; ++mi) {
        #pragma unroll
        for (int nj = 0; nj < 4; ++nj) {
            int nn = n0 + wn*64 + nj*16 + lm;
            #pragma unroll
            for (int r = 0; r < 4; ++r) {
                int co = co0 + wm*64 + mi*16 + lk*4 + r;
                atomicAdd(&Clin[(size_t)co*12800 + nn], acc[mi][nj][r]);
            }
        }
    }
#undef ALOAD
#undef BGLOAD
#undef AWRITE
}

// ---------------- K2b: Clin + bias -> up[b][unit][ch*400+rr], + partial ssq per (b,u) ----------------
__global__ void k_finalize_up(const float* __restrict__ Clin, const float* __restrict__ bias,
                              float* __restrict__ up, float* __restrict__ ssq) {
    __shared__ float r0[256], r1[256];
    int tid = threadIdx.x;
    int e = blockIdx.x*256 + tid;
    int co = e / 12800, n = e - co*12800;
    int unit = co >> 5, ch = co & 31;
    int bn = n / 400, rr = n - bn*400;
    float val = Clin[e] + bias[co];
    up[(size_t)(bn*8 + unit)*PDIM + ch*400 + rr] = val;
    // segmented squared-sum: block covers one co, n-range may straddle one 400-boundary
    int n0b = (blockIdx.x % 50) * 256;
    int bn0 = n0b / 400;
    int nb  = (bn0+1)*400 - n0b;           // split index within [0,256) or >=256
    float v2 = val * val;
    bool hi = (tid >= nb);
    r0[tid] = hi ? 0.f : v2;
    r1[tid] = hi ? v2 : 0.f;
    __syncthreads();
    for (int st = 128; st > 0; st >>= 1) {
        if (tid < st) { r0[tid] += r0[tid+st]; r1[tid] += r1[tid+st]; }
        __syncthreads();
    }
    if (tid == 0) {
        atomicAdd(&ssq[bn0*8 + unit], r0[0]);
        if (nb < 256) atomicAdd(&ssq[(bn0+1)*8 + unit], r1[0]);
    }
}

// ---------------- K3: xq[p][b*8+u] = up[b][u][p] * scl(b,u), scl from ssq ----------------
__global__ void k_xq(const float* __restrict__ up, const float* __restrict__ ssq,
                     float* __restrict__ xq) {
    __shared__ float sT[32][257];
    __shared__ float sS[256];
    int p0 = blockIdx.x*32, tid = threadIdx.x;
    {
        float q = ssq[tid];
        sS[tid] = sqrtf(q) / (1.f + q);
    }
    __syncthreads();
    for (int r = 0; r < 32; ++r) {
        int e = r*256 + tid;
        int bu = e >> 5, pi = e & 31;
        sT[pi][bu] = up[(size_t)bu*PDIM + p0 + pi] * sS[bu];
    }
    __syncthreads();
    for (int r = 0; r < 32; ++r)
        xq[(size_t)(p0+r)*256 + tid] = sT[r][tid];
}

// ---------------- K4: softmax-over-P stats per o ----------------
__global__ void k_softmax_stats(const float* __restrict__ bij, float* __restrict__ cstat) {
    __shared__ float red[256];
    int o = blockIdx.x, tid = threadIdx.x;
    float m = -1e30f;
    for (int i = tid; i < PDIM; i += 256) m = fmaxf(m, bij[i*10 + o]);
    red[tid] = m; __syncthreads();
    for (int st = 128; st > 0; st >>= 1) {
        if (tid < st) red[tid] = fmaxf(red[tid], red[tid+st]);
        __syncthreads();
    }
    m = red[0]; __syncthreads();
    float s = 0.f;
    for (int i = tid; i < PDIM; i += 256) s += __expf(bij[i*10 + o] - m);
    red[tid] = s; __syncthreads();
    for (int st = 128; st > 0; st >>= 1) {
        if (tid < st) red[tid] += red[tid+st];
        __syncthreads();
    }
    if (tid == 0) { cstat[o] = m; cstat[16 + o] = red[0]; }
}

// ---------------- K5: pass A — partial s_j, u_hat recomputed inline ----------------
__global__ __launch_bounds__(256) void k_route_sj(const float* __restrict__ Wd,
        const float* __restrict__ xq, const float* __restrict__ bij,
        const float* __restrict__ cstat, float* __restrict__ sjp) {
    int tid = threadIdx.x;
    int bq = tid & 31, g = tid >> 5;
    int os0 = g*20;
    int o0 = os0 >> 4, o1 = o0 + 1;
    float cm0 = cstat[o0], cm1 = cstat[o1];
    float rd0 = 1.f / cstat[16+o0], rd1 = 1.f / cstat[16+o1];
    float acc[20];
    #pragma unroll
    for (int i = 0; i < 20; ++i) acc[i] = 0.f;
    int p0 = blockIdx.x * 64;
    for (int p = p0; p < p0+64; ++p) {
        const float4* xr = (const float4*)(xq + (size_t)p*256 + bq*8);
        float4 xa = xr[0], xb = xr[1];
        float c0 = __expf(bij[p*10+o0] - cm0) * rd0;
        float c1 = __expf(bij[p*10+o1] - cm1) * rd1;
        const float4* wr = (const float4*)(Wd + (size_t)p*1280 + os0*8);
        #pragma unroll
        for (int i = 0; i < 20; ++i) {
            float4 w0 = wr[i*2], w1 = wr[i*2+1];
            float uh = w0.x*xa.x + w0.y*xa.y + w0.z*xa.z + w0.w*xa.w
                     + w1.x*xb.x + w1.y*xb.y + w1.z*xb.z + w1.w*xb.w;
            int oi = (os0 + i) >> 4;
            acc[i] += (oi == o0 ? c0 : c1) * uh;
        }
    }
    float* outp = sjp + (size_t)blockIdx.x*5120 + bq*OSD + os0;
    #pragma unroll
    for (int i = 0; i < 20; ++i) outp[i] = acc[i];
}

// ---------------- K6: reduce partials -> s_j -> squash over O -> v (+out) ----------------
__global__ void k_reduce_squash(const float* __restrict__ sjp, float* __restrict__ v,
                                float* __restrict__ dout, int writeOut) {
    __shared__ float ss[640];
    __shared__ float sc[64];
    int tid = threadIdx.x;
    int e = blockIdx.x*640 + tid;
    float s = 0.f;
    for (int k = 0; k < NBLK_A; ++k) s += sjp[(size_t)k*5120 + e];
    ss[tid] = s;
    __syncthreads();
    if (tid < 64) {
        int bl = tid >> 4, sl = tid & 15;
        float msq = 0.f;
        #pragma unroll
        for (int o = 0; o < 10; ++o) { float t_ = ss[bl*160 + o*16 + sl]; msq += t_*t_; }
        sc[tid] = sqrtf(msq) / (1.f + msq);
    }
    __syncthreads();
    int bl = tid / 160, r = tid - bl*160, sl = r & 15;
    float val = ss[tid] * sc[bl*16 + sl];
    v[e] = val;
    if (writeOut) dout[e] = val;
}

// ---------------- K7: pass B — b_ij += mean_b sum_s u_hat*v ----------------
__global__ __launch_bounds__(320) void k_route_bij(const float* __restrict__ Wd,
        const float* __restrict__ xq, const float* __restrict__ v,
        float* __restrict__ bij) {
    __shared__ float sv[5120];
    __shared__ float sxq[32*260];
    int tid = threadIdx.x;
    int p0 = blockIdx.x*32;
    for (int e = tid; e < 5120; e += 320) sv[e] = v[e];
    for (int e = tid; e < 8192; e += 320) {
        int pl = e >> 8, bu = e & 255;
        sxq[pl*260 + bu] = xq[(size_t)(p0+pl)*256 + bu];
    }
    __syncthreads();
    int pl = tid / 10, o = tid - pl*10;
    int p = p0 + pl;
    const float4* wr = (const float4*)(Wd + (size_t)p*1280 + o*128);
    float4 wreg[32];
    #pragma unroll
    for (int i = 0; i < 32; ++i) wreg[i] = wr[i];
    float acc = 0.f;
    for (int bq = 0; bq < 32; ++bq) {
        float4 x0 = *(const float4*)&sxq[pl*260 + bq*8];
        float4 x1 = *(const float4*)&sxq[pl*260 + bq*8 + 4];
        #pragma unroll
        for (int sg = 0; sg < 4; ++sg) {
            float4 vs = *(const float4*)&sv[bq*160 + o*16 + sg*4];
            float vsv[4] = {vs.x, vs.y, vs.z, vs.w};
            #pragma unroll
            for (int s4 = 0; s4 < 4; ++s4) {
                int s = sg*4 + s4;
                float4 w0 = wreg[s*2], w1 = wreg[s*2+1];
                float uh = w0.x*x0.x + w0.y*x0.y + w0.z*x0.z + w0.w*x0.w
                         + w1.x*x1.x + w1.y*x1.y + w1.z*x1.z + w1.w*x1.w;
                acc += uh * vsv[s4];
            }
        }
    }
    bij[p*10 + o] += acc * (1.f/32.f);
}

extern "C" void kernel_launch(void* const* d_in, const int* in_sizes, int n_in,
                              void* d_out, int out_size, void* d_ws, size_t ws_size,
                              hipStream_t stream) {
    const float* x   = (const float*)d_in[0];
    const float* c1w = (const float*)d_in[1];
    const float* c1b = (const float*)d_in[2];
    const float* pw  = (const float*)d_in[3];
    const float* pb  = (const float*)d_in[4];
    const float* Wd  = (const float*)d_in[5];
    float* out = (float*)d_out;

    // workspace map (bytes): total ~60.6 MB
    char* wsb = (char*)d_ws;
    _Float16* ht1 = (_Float16*)(wsb);                 // 12,845,056
    _Float16* ht2 = (_Float16*)(wsb + 12845056);      // 12,845,056
    float* Wkf  = (float*)(wsb + 25690112);           // 21,233,664
    float* Clin = (float*)(wsb + 46923776);           // 13,107,200
    char* tailb = wsb + 60030976;
    float* bij   = (float*)tailb;                     // 128000 f
    float* ssq   = bij + 128000;                      // 256 f
    float* cstat = ssq + 256;                         // 32 f
    float* vv    = cstat + 32;                        // 5120 f
    // aliases over dead regions:
    float* up  = (float*)(wsb + 25690112);   // over Wkf (dead after GEMM)
    float* xq  = (float*)(wsb);              // over ht planes (dead after GEMM)
    float* sjp = (float*)(wsb + 46923776);   // over Clin (dead after finalize)

    hipMemsetAsync(Clin, 0, 13107200, stream);
    hipMemsetAsync(bij, 0, (128000 + 256)*sizeof(float), stream);  // bij + ssq

    k_prep_w<<<256, 256, 0, stream>>>(pw, Wkf);
    k_conv1<<<dim3(32,16), 256, 0, stream>>>(x, c1w, c1b, ht1, ht2);
    k_prim_mfma<<<dim3(50,2,8), 512, 0, stream>>>(ht1, ht2, Wkf, Clin);
    k_finalize_up<<<12800, 256, 0, stream>>>(Clin, pb, up, ssq);
    k_xq<<<400, 256, 0, stream>>>(up, ssq, xq);

    for (int it = 0; it < 3; ++it) {
        k_softmax_stats<<<10, 256, 0, stream>>>(bij, cstat);
        k_route_sj<<<NBLK_A, 256, 0, stream>>>(Wd, xq, bij, cstat, sjp);
        k_reduce_squash<<<8, 640, 0, stream>>>(sjp, vv, out, it == 2 ? 1 : 0);
        if (it < 2)
            k_route_bij<<<400, 320, 0, stream>>>(Wd, xq, vv, bij);
    }
}